// Round 11
// baseline (222.533 us; speedup 1.0000x reference)
//
#include <hip/hip_runtime.h>
#include <hip/hip_bf16.h>

// Problem constants (fixed by reference)
#define B_ 16
#define L_ 24
#define N_ 256
#define E_ 4096
#define T_ (B_ * L_)   // 384 graphs

// All tensors float32. Output [B,L,N,64] f32 = 25.2 MB.
// X (LSTM h states, [T,N,64] f32) lives in d_out; k_graph overwrites its own
// tile in place. ws holds folded tables + pre-swizzled W_hh MFMA frags.
constexpr int WP    = 0;                   // P = W1a@W2b  (64x64)
constexpr int WRQ   = WP + 4096;           // RQ = W2a + Q (64x64), Q = W1b@W2b
constexpr int WRM   = WRQ + 4096;          // Q alone (for rare sel==0 correction)
constexpr int WBIAS = WRM + 4096;          // biasv [256][64]
constexpr int WALPHA= WBIAS + 16384;       // alpha[256]
constexpr int WBETA = WALPHA + 256;        // beta[256]
constexpr int WDINV = WBETA + 256;         // 1/max(cnt,1) [256]
constexpr int WSEL  = WDINV + 256;         // cnt>0 ? 1 : 0 [256]
constexpr int WSW   = WSEL + 256;          // sw0[256], sw1[256]
constexpr int WCNTF = WSW + 512;           // cnt as float [256]
constexpr int WCOLP = WCNTF + 256;         // 257 ints (CSR col ptr)
constexpr int WROWS = WCOLP + 260;         // 4096 ints
constexpr int WHFRAG= WROWS + 4096;        // W_hh bf16 MFMA frags, 2048 x 16B

using bf16x8 = __attribute__((ext_vector_type(8))) short;   // 8 bf16 (4 VGPRs)
using f32x4  = __attribute__((ext_vector_type(4))) float;   // MFMA C/D

__device__ __forceinline__ float sigm(float x) { return 1.f / (1.f + __expf(-x)); }
__device__ __forceinline__ float tanh_(float x) { return 2.f / (1.f + __expf(-2.f * x)) - 1.f; }
__device__ __forceinline__ float blo(unsigned u) { return __uint_as_float(u << 16); }
__device__ __forceinline__ float bhi(unsigned u) { return __uint_as_float(u & 0xffff0000u); }
__device__ __forceinline__ unsigned f2bf(float f) {   // RNE bf16 bits
    unsigned u = __float_as_uint(f);
    return (u + 0x7fffu + ((u >> 16) & 1u)) >> 16;
}

// ---- K1 fused prep: blk 0 = tables; blk 1..8 = P/RQ/Q; blk 9..12 = W frags
__global__ __launch_bounds__(256) void k_prep(
    const int* __restrict__ conn, const float* __restrict__ cw,
    const float* __restrict__ Wih, const float* __restrict__ embW,
    const float* __restrict__ embB, const float* __restrict__ bih,
    const float* __restrict__ bhh, const float* __restrict__ Whh,
    const float* __restrict__ m1W, const float* __restrict__ m1b,
    const float* __restrict__ m2W, const float* __restrict__ m2b,
    float* __restrict__ ws) {
    int t = threadIdx.x, blk = blockIdx.x;
    if (blk >= 9) {
        // W_hh -> bf16 B-fragments for mfma_f32_16x16x32_bf16.
        int idx = (blk - 9) * 256 + t;        // 0..1023
        for (int f = idx; f < 2048; f += 1024) {
            int p = f >> 6, l = f & 63;
            int ct = p >> 1, ks = p & 1;
            const float* src = Whh + (ct * 16 + (l & 15)) * 64 + ks * 32 + ((l >> 4) << 3);
            unsigned u[4];
            #pragma unroll
            for (int q = 0; q < 4; ++q)
                u[q] = f2bf(src[2 * q]) | (f2bf(src[2 * q + 1]) << 16);
            ((uint4*)(ws + WHFRAG))[f] = make_uint4(u[0], u[1], u[2], u[3]);
        }
        return;
    }
    if (blk > 0) {
        __shared__ float sB[64 * 64];   // W2b = m2W rows 64..127
        bool isP = blk <= 4;
        int kbase = ((blk - 1) & 3) * 16;
        #pragma unroll
        for (int i = 0; i < 16; ++i) sB[t + 256 * i] = m2W[64 * 64 + t + 256 * i];
        __syncthreads();
        int j = t & 63, kl = t >> 6;
        #pragma unroll
        for (int r = 0; r < 4; ++r) {
            int k = kbase + kl * 4 + r;
            const float* arow = m1W + (isP ? k : (64 + k)) * 64;
            float acc = 0.f;
            #pragma unroll
            for (int m = 0; m < 64; m += 4) {
                float4 a4 = *(const float4*)(arow + m);
                acc = fmaf(a4.x, sB[m * 64 + j], acc);
                acc = fmaf(a4.y, sB[(m + 1) * 64 + j], acc);
                acc = fmaf(a4.z, sB[(m + 2) * 64 + j], acc);
                acc = fmaf(a4.w, sB[(m + 3) * 64 + j], acc);
            }
            if (isP) {
                ws[WP + k * 64 + j] = acc;
            } else {
                ws[WRM + k * 64 + j] = acc;                       // Q
                ws[WRQ + k * 64 + j] = acc + m2W[k * 64 + j];     // W2a + Q
            }
        }
        return;
    }
    __shared__ int s_cnt[N_];
    __shared__ float s_sw0[N_], s_sw1[N_];
    __shared__ int s_pos[N_];
    __shared__ float sU[3 * 64];
    __shared__ int s_wsum[4];
    s_cnt[t] = 0; s_sw0[t] = 0.f; s_sw1[t] = 0.f;
    __syncthreads();
    for (int e = t; e < E_; e += 256) {
        int c = conn[E_ + e] & 255;
        atomicAdd(&s_cnt[c], 1);
        atomicAdd(&s_sw0[c], cw[2 * e]);
        atomicAdd(&s_sw1[c], cw[2 * e + 1]);
    }
    __syncthreads();
    int lane = t & 63, wv = t >> 6;
    int val = s_cnt[t];
    int inc = val;
    #pragma unroll
    for (int d = 1; d < 64; d <<= 1) {
        int y = __shfl_up(inc, d);
        if (lane >= d) inc += y;
    }
    if (lane == 63) s_wsum[wv] = inc;
    __syncthreads();
    int wadd = 0;
    for (int w = 0; w < wv; ++w) wadd += s_wsum[w];
    int excl = wadd + inc - val;
    int* colp = (int*)(ws + WCOLP);
    colp[t] = excl;
    if (t == 0) colp[N_] = E_;
    s_pos[t] = excl;
    int cnt = val;
    ws[WCNTF + t] = (float)cnt;
    ws[WDINV + t] = 1.f / (float)(cnt > 1 ? cnt : 1);
    ws[WSEL + t]  = cnt > 0 ? 1.f : 0.f;
    ws[WSW + t]        = s_sw0[t];
    ws[WSW + N_ + t]   = s_sw1[t];
    float a = 0.f, b = 0.f;
    #pragma unroll
    for (int i = 0; i < 16; ++i) {
        float w = Wih[t * 16 + i];
        a += w * embW[i];
        b += w * embB[i];
    }
    ws[WALPHA + t] = a;
    ws[WBETA + t]  = b + bih[t] + bhh[t];
    __syncthreads();   // all s_pos[] initialized before rows fill
    int* rows = (int*)(ws + WROWS);
    for (int e = t; e < E_; e += 256) {
        int c = conn[E_ + e] & 255;
        int p = atomicAdd(&s_pos[c], 1);
        rows[p] = conn[e] & 255;
    }
    if (t < 192) {
        int part = t >> 6, j = t & 63;
        float acc = 0.f;
        #pragma unroll 8
        for (int m = 0; m < 64; ++m) {
            float w = (part == 0) ? m1W[128 * 64 + m]
                    : (part == 1) ? m1W[129 * 64 + m] : m1b[m];
            acc = fmaf(w, m2W[(64 + m) * 64 + j], acc);
        }
        sU[part * 64 + j] = acc;
    }
    __syncthreads();
    {
        int j = t & 63;
        float u0 = sU[j], u1 = sU[64 + j], u2 = sU[128 + j];
        float b2j = m2b[j];
        int vb = t >> 6;
        #pragma unroll 8
        for (int i = 0; i < 64; ++i) {
            int v = vb + i * 4;
            int cv = s_cnt[v];
            float dv = 1.f / (float)(cv > 1 ? cv : 1);
            float bb = s_sw0[v] * u0 + s_sw1[v] * u1 + (float)cv * u2;
            ws[WBIAS + v * 64 + j] = dv * bb + b2j;
        }
    }
}

// ------- K2: MFMA LSTM. block = 16 seqs, 4 waves split the 16 col-tiles -----
// (frozen from round 10 — it took k_lstm out of the top-5)
constexpr int HS = 72;   // h tile row stride in shorts (16B-aligned rows)

__global__ __launch_bounds__(256, 1) void k_lstm(
    const float* __restrict__ aqi, const float* __restrict__ ws,
    float* __restrict__ xout) {
    __shared__ __align__(16) short sW[2048 * 8];        // 32 KB: W frags
    __shared__ __align__(16) short sHhi[2][16 * HS];    // h_hi, 2 step-parity bufs
    __shared__ __align__(16) short sHlo[2][16 * HS];
    __shared__ float sX[24 * 16];                       // x[l][seq-row]
    int t = threadIdx.x;
    int w = t >> 6, lane = t & 63;
    int seq0 = blockIdx.x * 16;
    int b0 = seq0 >> 8, n0 = seq0 & 255;
    {
        const uint4* src = (const uint4*)(ws + WHFRAG);
        uint4* dst = (uint4*)sW;
        #pragma unroll
        for (int i = 0; i < 8; ++i) dst[t + 256 * i] = src[t + 256 * i];
    }
    for (int i = t; i < 384; i += 256) {
        int l = i >> 4, c = i & 15;
        sX[l * 16 + c] = aqi[(b0 * L_ + l) * N_ + n0 + c];
    }
    int c0 = lane & 15, quad = lane >> 4, q4 = quad * 4, q8 = quad * 8;
    float alF[4], beF[4];
    #pragma unroll
    for (int g = 0; g < 4; ++g) {
        alF[g] = ws[WALPHA + (4 * g + w) * 16 + c0];
        beF[g] = ws[WBETA  + (4 * g + w) * 16 + c0];
    }
    float cst[4] = {0.f, 0.f, 0.f, 0.f};
    bf16x8 hA[2][2] = {};
    __syncthreads();
    for (int l = 0; l < L_; ++l) {
        int buf = l & 1;
        f32x4 acc[4];
        #pragma unroll
        for (int g = 0; g < 4; ++g) {
            #pragma unroll
            for (int r = 0; r < 4; ++r)
                acc[g][r] = fmaf(sX[l * 16 + q4 + r], alF[g], beF[g]);
        }
        if (l > 0) {
            #pragma unroll
            for (int g = 0; g < 4; ++g) {
                int ct = 4 * g + w;
                #pragma unroll
                for (int ks = 0; ks < 2; ++ks) {
                    bf16x8 wb = *(const bf16x8*)&sW[((ct * 2 + ks) * 64 + lane) * 8];
                    acc[g] = __builtin_amdgcn_mfma_f32_16x16x32_bf16(
                        hA[0][ks], wb, acc[g], 0, 0, 0);
                    acc[g] = __builtin_amdgcn_mfma_f32_16x16x32_bf16(
                        hA[1][ks], wb, acc[g], 0, 0, 0);
                }
            }
        }
        float* orow = xout + ((size_t)(b0 * L_ + l) * N_ + n0) * 64;
        #pragma unroll
        for (int r = 0; r < 4; ++r) {
            float iv = sigm(acc[0][r]);
            float fv = sigm(acc[1][r]);
            float gv = tanh_(acc[2][r]);
            float ov = sigm(acc[3][r]);
            cst[r] = fmaf(fv, cst[r], iv * gv);
            float h = ov * tanh_(cst[r]);
            orow[(q4 + r) * 64 + w * 16 + c0] = h;
            unsigned hb = f2bf(h);
            float hf = __uint_as_float(hb << 16);
            unsigned lb = f2bf(h - hf);
            sHhi[buf][(q4 + r) * HS + w * 16 + c0] = (short)hb;
            sHlo[buf][(q4 + r) * HS + w * 16 + c0] = (short)lb;
        }
        __syncthreads();
        hA[0][0] = *(const bf16x8*)&sHhi[buf][c0 * HS + q8];
        hA[0][1] = *(const bf16x8*)&sHhi[buf][c0 * HS + 32 + q8];
        hA[1][0] = *(const bf16x8*)&sHlo[buf][c0 * HS + q8];
        hA[1][1] = *(const bf16x8*)&sHlo[buf][c0 * HS + 32 + q8];
    }
}

// ------- K4: per-graph GNN. ALL private-array indices compile-time const ----
// (fix: full unrolls -> S[64]/acc[64] stay in VGPRs, no scratch spills)
constexpr int XS = 66;  // bf16 LDS row stride: 33 words (odd -> full bank spread)

__global__ __launch_bounds__(256, 2) void k_graph(
    const float* __restrict__ ws, const float* __restrict__ m2W,
    float* __restrict__ out) {
    __shared__ __hip_bfloat16 Xl[N_ * XS];   // 33.8 KB
    int tg = blockIdx.x;
    int tid = threadIdx.x;
    const float4* src = (const float4*)(out + tg * (N_ * 64));
    #pragma unroll
    for (int it = 0; it < 16; ++it) {
        int idx = tid + it * 256;
        float4 d = src[idx];
        int node = idx >> 4, col = (idx & 15) * 4;
        __hip_bfloat162 p0 = __halves2bfloat162(__float2bfloat16(d.x), __float2bfloat16(d.y));
        __hip_bfloat162 p1 = __halves2bfloat162(__float2bfloat16(d.z), __float2bfloat16(d.w));
        unsigned* dst = (unsigned*)&Xl[node * XS + col];
        dst[0] = *(unsigned*)&p0;
        dst[1] = *(unsigned*)&p1;
    }
    __syncthreads();
    int v = tid;
    float S[64];
    #pragma unroll
    for (int k = 0; k < 64; ++k) S[k] = 0.f;
    {
        const int* colp = (const int*)(ws + WCOLP);
        const int* rows = (const int*)(ws + WROWS);
        int e1 = colp[v + 1];
        for (int e = colp[v]; e < e1; ++e) {
            int r = rows[e];
            const unsigned* xp = (const unsigned*)(Xl + r * XS);
            #pragma unroll
            for (int w = 0; w < 32; ++w) {
                unsigned u = xp[w];
                S[2 * w]     += blo(u);
                S[2 * w + 1] += bhi(u);
            }
        }
    }
    float dinv = ws[WDINV + v];
    float sel  = ws[WSEL + v];
    float acc[64];
    {
        const float* bv = ws + WBIAS + v * 64;
        #pragma unroll
        for (int j = 0; j < 64; j += 4) {
            float4 b4 = *(const float4*)(bv + j);
            acc[j] = b4.x; acc[j + 1] = b4.y; acc[j + 2] = b4.z; acc[j + 3] = b4.w;
        }
    }
    // S part: acc += (dinv*S) @ P.  FULL unroll: S[k] must be const-indexed.
    {
        const float* Pm = ws + WP;
        #pragma unroll
        for (int k = 0; k < 64; ++k) {
            float sv = dinv * S[k];
            const float* Pr = Pm + k * 64;
            #pragma unroll
            for (int j = 0; j < 64; j += 4) {
                float4 p = *(const float4*)(Pr + j);
                acc[j]     = fmaf(sv, p.x, acc[j]);
                acc[j + 1] = fmaf(sv, p.y, acc[j + 1]);
                acc[j + 2] = fmaf(sv, p.z, acc[j + 2]);
                acc[j + 3] = fmaf(sv, p.w, acc[j + 3]);
            }
        }
    }
    // x part: acc += x[v] @ RQ  (acc indices const after inner unroll)
    {
        const unsigned* xrow = (const unsigned*)(Xl + v * XS);
        const float* Mm = ws + WRQ;
        #pragma unroll 4
        for (int kk = 0; kk < 32; ++kk) {
            unsigned u = xrow[kk];
            float x0 = blo(u), x1 = bhi(u);
            const float* M0 = Mm + (2 * kk) * 64;
            const float* M1 = M0 + 64;
            #pragma unroll
            for (int j = 0; j < 64; j += 4) {
                float4 m0 = *(const float4*)(M0 + j);
                float4 m1 = *(const float4*)(M1 + j);
                acc[j]     = fmaf(x0, m0.x, fmaf(x1, m1.x, acc[j]));
                acc[j + 1] = fmaf(x0, m0.y, fmaf(x1, m1.y, acc[j + 1]));
                acc[j + 2] = fmaf(x0, m0.z, fmaf(x1, m1.z, acc[j + 2]));
                acc[j + 3] = fmaf(x0, m0.w, fmaf(x1, m1.w, acc[j + 3]));
            }
        }
    }
    // rare correction (cnt==0): FULL unrolls so acc[] stays const-indexed
    if (sel < 0.5f) {
        const unsigned* xrow = (const unsigned*)(Xl + v * XS);
        const float* Qm = ws + WRM;
        #pragma unroll
        for (int kk = 0; kk < 32; ++kk) {
            unsigned u = xrow[kk];
            float x0 = blo(u), x1 = bhi(u);
            const float* Q0 = Qm + (2 * kk) * 64;
            const float* Q1 = Q0 + 64;
            #pragma unroll
            for (int j = 0; j < 64; ++j)
                acc[j] -= x0 * Q0[j] + x1 * Q1[j];
        }
    }
    float* og = out + (tg * N_ + v) * 64;
    #pragma unroll
    for (int j = 0; j < 64; j += 4) {
        *(float4*)(og + j) = make_float4(acc[j], acc[j + 1], acc[j + 2], acc[j + 3]);
    }
}

extern "C" void kernel_launch(void* const* d_in, const int* in_sizes, int n_in,
                              void* d_out, int out_size, void* d_ws, size_t ws_size,
                              hipStream_t stream) {
    const float* aqi  = (const float*)d_in[0];
    const int*   conn = (const int*)d_in[1];
    const float* cw   = (const float*)d_in[2];
    const float* embW = (const float*)d_in[3];
    const float* embB = (const float*)d_in[4];
    const float* Wih  = (const float*)d_in[5];
    const float* Whh  = (const float*)d_in[6];
    const float* bih  = (const float*)d_in[7];
    const float* bhh  = (const float*)d_in[8];
    const float* m1W  = (const float*)d_in[9];
    const float* m1b  = (const float*)d_in[10];
    const float* m2W  = (const float*)d_in[11];
    const float* m2b  = (const float*)d_in[12];
    float* ws  = (float*)d_ws;
    float* out = (float*)d_out;

    k_prep<<<dim3(13), dim3(256), 0, stream>>>(conn, cw, Wih, embW, embB, bih, bhh,
                                               Whh, m1W, m1b, m2W, m2b, ws);
    k_lstm<<<dim3(256), dim3(256), 0, stream>>>(aqi, ws, out);
    k_graph<<<dim3(T_), dim3(256), 0, stream>>>(ws, m2W, out);
}

// Round 12
// 216.090 us; speedup vs baseline: 1.0298x; 1.0298x over previous
//
#include <hip/hip_runtime.h>
#include <hip/hip_bf16.h>

// Problem constants (fixed by reference)
#define B_ 16
#define L_ 24
#define N_ 256
#define E_ 4096
#define T_ (B_ * L_)   // 384 graphs

// All tensors float32. Output [B,L,N,64] f32 = 25.2 MB.
// X (LSTM h states, [T,N,64] f32) lives in d_out; k_graph overwrites its own
// tile in place. ws holds folded tables + pre-swizzled W_hh MFMA frags.
constexpr int WP    = 0;                   // P = W1a@W2b  (64x64)
constexpr int WRQ   = WP + 4096;           // RQ = W2a + Q (64x64), Q = W1b@W2b
constexpr int WRM   = WRQ + 4096;          // Q alone (for rare sel==0 correction)
constexpr int WBIAS = WRM + 4096;          // biasv [256][64]
constexpr int WALPHA= WBIAS + 16384;       // alpha[256]
constexpr int WBETA = WALPHA + 256;        // beta[256]
constexpr int WDINV = WBETA + 256;         // 1/max(cnt,1) [256]
constexpr int WSEL  = WDINV + 256;         // cnt>0 ? 1 : 0 [256]
constexpr int WSW   = WSEL + 256;          // sw0[256], sw1[256]
constexpr int WCNTF = WSW + 512;           // cnt as float [256]
constexpr int WCOLP = WCNTF + 256;         // 257 ints (CSR col ptr)
constexpr int WROWS = WCOLP + 260;         // 4096 ints
constexpr int WHFRAG= WROWS + 4096;        // W_hh bf16 MFMA frags, 2048 x 16B

using bf16x8 = __attribute__((ext_vector_type(8))) short;   // 8 bf16 (4 VGPRs)
using f32x4  = __attribute__((ext_vector_type(4))) float;   // MFMA C/D

__device__ __forceinline__ float sigm(float x) { return 1.f / (1.f + __expf(-x)); }
__device__ __forceinline__ float tanh_(float x) { return 2.f / (1.f + __expf(-2.f * x)) - 1.f; }
__device__ __forceinline__ float blo(unsigned u) { return __uint_as_float(u << 16); }
__device__ __forceinline__ float bhi(unsigned u) { return __uint_as_float(u & 0xffff0000u); }
__device__ __forceinline__ unsigned f2bf(float f) {   // RNE bf16 bits
    unsigned u = __float_as_uint(f);
    return (u + 0x7fffu + ((u >> 16) & 1u)) >> 16;
}

// ---- K1 fused prep: blk 0 = tables; blk 1..8 = P/RQ/Q; blk 9..12 = W frags
__global__ __launch_bounds__(256) void k_prep(
    const int* __restrict__ conn, const float* __restrict__ cw,
    const float* __restrict__ Wih, const float* __restrict__ embW,
    const float* __restrict__ embB, const float* __restrict__ bih,
    const float* __restrict__ bhh, const float* __restrict__ Whh,
    const float* __restrict__ m1W, const float* __restrict__ m1b,
    const float* __restrict__ m2W, const float* __restrict__ m2b,
    float* __restrict__ ws) {
    int t = threadIdx.x, blk = blockIdx.x;
    if (blk >= 9) {
        // W_hh -> bf16 B-fragments for mfma_f32_16x16x32_bf16.
        int idx = (blk - 9) * 256 + t;        // 0..1023
        for (int f = idx; f < 2048; f += 1024) {
            int p = f >> 6, l = f & 63;
            int ct = p >> 1, ks = p & 1;
            const float* src = Whh + (ct * 16 + (l & 15)) * 64 + ks * 32 + ((l >> 4) << 3);
            unsigned u[4];
            #pragma unroll
            for (int q = 0; q < 4; ++q)
                u[q] = f2bf(src[2 * q]) | (f2bf(src[2 * q + 1]) << 16);
            ((uint4*)(ws + WHFRAG))[f] = make_uint4(u[0], u[1], u[2], u[3]);
        }
        return;
    }
    if (blk > 0) {
        __shared__ float sB[64 * 64];   // W2b = m2W rows 64..127
        bool isP = blk <= 4;
        int kbase = ((blk - 1) & 3) * 16;
        #pragma unroll
        for (int i = 0; i < 16; ++i) sB[t + 256 * i] = m2W[64 * 64 + t + 256 * i];
        __syncthreads();
        int j = t & 63, kl = t >> 6;
        #pragma unroll
        for (int r = 0; r < 4; ++r) {
            int k = kbase + kl * 4 + r;
            const float* arow = m1W + (isP ? k : (64 + k)) * 64;
            float acc = 0.f;
            #pragma unroll
            for (int m = 0; m < 64; m += 4) {
                float4 a4 = *(const float4*)(arow + m);
                acc = fmaf(a4.x, sB[m * 64 + j], acc);
                acc = fmaf(a4.y, sB[(m + 1) * 64 + j], acc);
                acc = fmaf(a4.z, sB[(m + 2) * 64 + j], acc);
                acc = fmaf(a4.w, sB[(m + 3) * 64 + j], acc);
            }
            if (isP) {
                ws[WP + k * 64 + j] = acc;
            } else {
                ws[WRM + k * 64 + j] = acc;                       // Q
                ws[WRQ + k * 64 + j] = acc + m2W[k * 64 + j];     // W2a + Q
            }
        }
        return;
    }
    __shared__ int s_cnt[N_];
    __shared__ float s_sw0[N_], s_sw1[N_];
    __shared__ int s_pos[N_];
    __shared__ float sU[3 * 64];
    __shared__ int s_wsum[4];
    s_cnt[t] = 0; s_sw0[t] = 0.f; s_sw1[t] = 0.f;
    __syncthreads();
    for (int e = t; e < E_; e += 256) {
        int c = conn[E_ + e] & 255;
        atomicAdd(&s_cnt[c], 1);
        atomicAdd(&s_sw0[c], cw[2 * e]);
        atomicAdd(&s_sw1[c], cw[2 * e + 1]);
    }
    __syncthreads();
    int lane = t & 63, wv = t >> 6;
    int val = s_cnt[t];
    int inc = val;
    #pragma unroll
    for (int d = 1; d < 64; d <<= 1) {
        int y = __shfl_up(inc, d);
        if (lane >= d) inc += y;
    }
    if (lane == 63) s_wsum[wv] = inc;
    __syncthreads();
    int wadd = 0;
    for (int w = 0; w < wv; ++w) wadd += s_wsum[w];
    int excl = wadd + inc - val;
    int* colp = (int*)(ws + WCOLP);
    colp[t] = excl;
    if (t == 0) colp[N_] = E_;
    s_pos[t] = excl;
    int cnt = val;
    ws[WCNTF + t] = (float)cnt;
    ws[WDINV + t] = 1.f / (float)(cnt > 1 ? cnt : 1);
    ws[WSEL + t]  = cnt > 0 ? 1.f : 0.f;
    ws[WSW + t]        = s_sw0[t];
    ws[WSW + N_ + t]   = s_sw1[t];
    float a = 0.f, b = 0.f;
    #pragma unroll
    for (int i = 0; i < 16; ++i) {
        float w = Wih[t * 16 + i];
        a += w * embW[i];
        b += w * embB[i];
    }
    ws[WALPHA + t] = a;
    ws[WBETA + t]  = b + bih[t] + bhh[t];
    __syncthreads();   // all s_pos[] initialized before rows fill
    int* rows = (int*)(ws + WROWS);
    for (int e = t; e < E_; e += 256) {
        int c = conn[E_ + e] & 255;
        int p = atomicAdd(&s_pos[c], 1);
        rows[p] = conn[e] & 255;
    }
    if (t < 192) {
        int part = t >> 6, j = t & 63;
        float acc = 0.f;
        #pragma unroll 8
        for (int m = 0; m < 64; ++m) {
            float w = (part == 0) ? m1W[128 * 64 + m]
                    : (part == 1) ? m1W[129 * 64 + m] : m1b[m];
            acc = fmaf(w, m2W[(64 + m) * 64 + j], acc);
        }
        sU[part * 64 + j] = acc;
    }
    __syncthreads();
    {
        int j = t & 63;
        float u0 = sU[j], u1 = sU[64 + j], u2 = sU[128 + j];
        float b2j = m2b[j];
        int vb = t >> 6;
        #pragma unroll 8
        for (int i = 0; i < 64; ++i) {
            int v = vb + i * 4;
            int cv = s_cnt[v];
            float dv = 1.f / (float)(cv > 1 ? cv : 1);
            float bb = s_sw0[v] * u0 + s_sw1[v] * u1 + (float)cv * u2;
            ws[WBIAS + v * 64 + j] = dv * bb + b2j;
        }
    }
}

// ------- K2: MFMA LSTM. block = 16 seqs, 4 waves split the 16 col-tiles -----
// (frozen from round 10)
constexpr int HS = 72;   // h tile row stride in shorts (16B-aligned rows)

__global__ __launch_bounds__(256, 1) void k_lstm(
    const float* __restrict__ aqi, const float* __restrict__ ws,
    float* __restrict__ xout) {
    __shared__ __align__(16) short sW[2048 * 8];        // 32 KB: W frags
    __shared__ __align__(16) short sHhi[2][16 * HS];    // h_hi, 2 step-parity bufs
    __shared__ __align__(16) short sHlo[2][16 * HS];
    __shared__ float sX[24 * 16];                       // x[l][seq-row]
    int t = threadIdx.x;
    int w = t >> 6, lane = t & 63;
    int seq0 = blockIdx.x * 16;
    int b0 = seq0 >> 8, n0 = seq0 & 255;
    {
        const uint4* src = (const uint4*)(ws + WHFRAG);
        uint4* dst = (uint4*)sW;
        #pragma unroll
        for (int i = 0; i < 8; ++i) dst[t + 256 * i] = src[t + 256 * i];
    }
    for (int i = t; i < 384; i += 256) {
        int l = i >> 4, c = i & 15;
        sX[l * 16 + c] = aqi[(b0 * L_ + l) * N_ + n0 + c];
    }
    int c0 = lane & 15, quad = lane >> 4, q4 = quad * 4, q8 = quad * 8;
    float alF[4], beF[4];
    #pragma unroll
    for (int g = 0; g < 4; ++g) {
        alF[g] = ws[WALPHA + (4 * g + w) * 16 + c0];
        beF[g] = ws[WBETA  + (4 * g + w) * 16 + c0];
    }
    float cst[4] = {0.f, 0.f, 0.f, 0.f};
    bf16x8 hA[2][2] = {};
    __syncthreads();
    for (int l = 0; l < L_; ++l) {
        int buf = l & 1;
        f32x4 acc[4];
        #pragma unroll
        for (int g = 0; g < 4; ++g) {
            #pragma unroll
            for (int r = 0; r < 4; ++r)
                acc[g][r] = fmaf(sX[l * 16 + q4 + r], alF[g], beF[g]);
        }
        if (l > 0) {
            #pragma unroll
            for (int g = 0; g < 4; ++g) {
                int ct = 4 * g + w;
                #pragma unroll
                for (int ks = 0; ks < 2; ++ks) {
                    bf16x8 wb = *(const bf16x8*)&sW[((ct * 2 + ks) * 64 + lane) * 8];
                    acc[g] = __builtin_amdgcn_mfma_f32_16x16x32_bf16(
                        hA[0][ks], wb, acc[g], 0, 0, 0);
                    acc[g] = __builtin_amdgcn_mfma_f32_16x16x32_bf16(
                        hA[1][ks], wb, acc[g], 0, 0, 0);
                }
            }
        }
        float* orow = xout + ((size_t)(b0 * L_ + l) * N_ + n0) * 64;
        #pragma unroll
        for (int r = 0; r < 4; ++r) {
            float iv = sigm(acc[0][r]);
            float fv = sigm(acc[1][r]);
            float gv = tanh_(acc[2][r]);
            float ov = sigm(acc[3][r]);
            cst[r] = fmaf(fv, cst[r], iv * gv);
            float h = ov * tanh_(cst[r]);
            orow[(q4 + r) * 64 + w * 16 + c0] = h;
            unsigned hb = f2bf(h);
            float hf = __uint_as_float(hb << 16);
            unsigned lb = f2bf(h - hf);
            sHhi[buf][(q4 + r) * HS + w * 16 + c0] = (short)hb;
            sHlo[buf][(q4 + r) * HS + w * 16 + c0] = (short)lb;
        }
        __syncthreads();
        hA[0][0] = *(const bf16x8*)&sHhi[buf][c0 * HS + q8];
        hA[0][1] = *(const bf16x8*)&sHhi[buf][c0 * HS + 32 + q8];
        hA[1][0] = *(const bf16x8*)&sHlo[buf][c0 * HS + q8];
        hA[1][1] = *(const bf16x8*)&sHlo[buf][c0 * HS + 32 + q8];
    }
}

// ------- K4: per-graph GNN. P/RQ staged in LDS (kill global-load stalls) ----
// All private-array indices compile-time const (no spills).
constexpr int XS = 72;  // bf16 LDS row stride: 16B-aligned rows for b128 reads

__global__ __launch_bounds__(256, 2) void k_graph(
    const float* __restrict__ ws, const float* __restrict__ m2W,
    float* __restrict__ out) {
    __shared__ __align__(16) __hip_bfloat16 Xl[N_ * XS];  // 36.9 KB
    __shared__ __align__(16) float sP[64 * 64];           // 16 KB
    __shared__ __align__(16) float sRQ[64 * 64];          // 16 KB
    int tg = blockIdx.x;
    int tid = threadIdx.x;
    // stage X (f32 -> bf16 LDS)
    const float4* src = (const float4*)(out + tg * (N_ * 64));
    #pragma unroll
    for (int it = 0; it < 16; ++it) {
        int idx = tid + it * 256;
        float4 d = src[idx];
        int node = idx >> 4, col = (idx & 15) * 4;
        __hip_bfloat162 p0 = __halves2bfloat162(__float2bfloat16(d.x), __float2bfloat16(d.y));
        __hip_bfloat162 p1 = __halves2bfloat162(__float2bfloat16(d.z), __float2bfloat16(d.w));
        *(uint2*)&Xl[node * XS + col] = make_uint2(*(unsigned*)&p0, *(unsigned*)&p1);
    }
    // stage P and RQ (f32, once per block)
    {
        const float4* pg = (const float4*)(ws + WP);
        const float4* rg = (const float4*)(ws + WRQ);
        float4* pl = (float4*)sP;
        float4* rl = (float4*)sRQ;
        #pragma unroll
        for (int i = 0; i < 4; ++i) {
            pl[tid + 256 * i] = pg[tid + 256 * i];
            rl[tid + 256 * i] = rg[tid + 256 * i];
        }
    }
    __syncthreads();
    int v = tid;
    // ---- gather S[64] = sum of in-neighbor x rows (uint4 LDS reads) ----
    float S[64];
    #pragma unroll
    for (int k = 0; k < 64; ++k) S[k] = 0.f;
    {
        const int* colp = (const int*)(ws + WCOLP);
        const int* rows = (const int*)(ws + WROWS);
        int e1 = colp[v + 1];
        for (int e = colp[v]; e < e1; ++e) {
            int r = rows[e];
            const uint4* xp = (const uint4*)(Xl + r * XS);
            #pragma unroll
            for (int w = 0; w < 8; ++w) {
                uint4 u = xp[w];
                S[8 * w]     += blo(u.x);
                S[8 * w + 1] += bhi(u.x);
                S[8 * w + 2] += blo(u.y);
                S[8 * w + 3] += bhi(u.y);
                S[8 * w + 4] += blo(u.z);
                S[8 * w + 5] += bhi(u.z);
                S[8 * w + 6] += blo(u.w);
                S[8 * w + 7] += bhi(u.w);
            }
        }
    }
    float dinv = ws[WDINV + v];
    float sel  = ws[WSEL + v];
    float acc[64];
    {
        const float* bv = ws + WBIAS + v * 64;
        #pragma unroll
        for (int j = 0; j < 64; j += 4) {
            float4 b4 = *(const float4*)(bv + j);
            acc[j] = b4.x; acc[j + 1] = b4.y; acc[j + 2] = b4.z; acc[j + 3] = b4.w;
        }
    }
    // S part: acc += (dinv*S) @ P  (LDS broadcast reads, full unroll)
    {
        #pragma unroll
        for (int k = 0; k < 64; ++k) {
            float sv = dinv * S[k];
            const float* Pr = sP + k * 64;
            #pragma unroll
            for (int j = 0; j < 64; j += 4) {
                float4 p = *(const float4*)(Pr + j);
                acc[j]     = fmaf(sv, p.x, acc[j]);
                acc[j + 1] = fmaf(sv, p.y, acc[j + 1]);
                acc[j + 2] = fmaf(sv, p.z, acc[j + 2]);
                acc[j + 3] = fmaf(sv, p.w, acc[j + 3]);
            }
        }
    }
    // x part: acc += x[v] @ RQ  (LDS broadcast reads)
    {
        const unsigned* xrow = (const unsigned*)(Xl + v * XS);
        #pragma unroll 4
        for (int kk = 0; kk < 32; ++kk) {
            unsigned u = xrow[kk];
            float x0 = blo(u), x1 = bhi(u);
            const float* M0 = sRQ + (2 * kk) * 64;
            const float* M1 = M0 + 64;
            #pragma unroll
            for (int j = 0; j < 64; j += 4) {
                float4 m0 = *(const float4*)(M0 + j);
                float4 m1 = *(const float4*)(M1 + j);
                acc[j]     = fmaf(x0, m0.x, fmaf(x1, m1.x, acc[j]));
                acc[j + 1] = fmaf(x0, m0.y, fmaf(x1, m1.y, acc[j + 1]));
                acc[j + 2] = fmaf(x0, m0.z, fmaf(x1, m1.z, acc[j + 2]));
                acc[j + 3] = fmaf(x0, m0.w, fmaf(x1, m1.w, acc[j + 3]));
            }
        }
    }
    // rare correction (cnt==0): full unrolls, reads Q from global (cold path)
    if (sel < 0.5f) {
        const unsigned* xrow = (const unsigned*)(Xl + v * XS);
        const float* Qm = ws + WRM;
        #pragma unroll
        for (int kk = 0; kk < 32; ++kk) {
            unsigned u = xrow[kk];
            float x0 = blo(u), x1 = bhi(u);
            const float* Q0 = Qm + (2 * kk) * 64;
            const float* Q1 = Q0 + 64;
            #pragma unroll
            for (int j = 0; j < 64; ++j)
                acc[j] -= x0 * Q0[j] + x1 * Q1[j];
        }
    }
    float* og = out + (tg * N_ + v) * 64;
    #pragma unroll
    for (int j = 0; j < 64; j += 4) {
        *(float4*)(og + j) = make_float4(acc[j], acc[j + 1], acc[j + 2], acc[j + 3]);
    }
}

extern "C" void kernel_launch(void* const* d_in, const int* in_sizes, int n_in,
                              void* d_out, int out_size, void* d_ws, size_t ws_size,
                              hipStream_t stream) {
    const float* aqi  = (const float*)d_in[0];
    const int*   conn = (const int*)d_in[1];
    const float* cw   = (const float*)d_in[2];
    const float* embW = (const float*)d_in[3];
    const float* embB = (const float*)d_in[4];
    const float* Wih  = (const float*)d_in[5];
    const float* Whh  = (const float*)d_in[6];
    const float* bih  = (const float*)d_in[7];
    const float* bhh  = (const float*)d_in[8];
    const float* m1W  = (const float*)d_in[9];
    const float* m1b  = (const float*)d_in[10];
    const float* m2W  = (const float*)d_in[11];
    const float* m2b  = (const float*)d_in[12];
    float* ws  = (float*)d_ws;
    float* out = (float*)d_out;

    k_prep<<<dim3(13), dim3(256), 0, stream>>>(conn, cw, Wih, embW, embB, bih, bhh,
                                               Whh, m1W, m1b, m2W, m2b, ws);
    k_lstm<<<dim3(256), dim3(256), 0, stream>>>(aqi, ws, out);
    k_graph<<<dim3(T_), dim3(256), 0, stream>>>(ws, m2W, out);
}

// Round 13
// 176.184 us; speedup vs baseline: 1.2631x; 1.2265x over previous
//
#include <hip/hip_runtime.h>
#include <hip/hip_bf16.h>

// Problem constants (fixed by reference)
#define B_ 16
#define L_ 24
#define N_ 256
#define E_ 4096
#define T_ (B_ * L_)   // 384 graphs

// All tensors float32. Output [B,L,N,64] f32 = 25.2 MB.
// X (LSTM h states, [T,N,64] f32) lives in d_out; k_graph overwrites its own
// tile in place. ws holds folded tables + pre-swizzled MFMA fragments.
constexpr int WP    = 0;                   // P = W1a@W2b  (64x64)
constexpr int WRQ   = WP + 4096;           // RQ = W2a + Q (64x64), Q = W1b@W2b
constexpr int WRM   = WRQ + 4096;          // Q alone (for rare sel==0 correction)
constexpr int WBIAS = WRM + 4096;          // biasv [256][64]
constexpr int WALPHA= WBIAS + 16384;       // alpha[256]
constexpr int WBETA = WALPHA + 256;        // beta[256]
constexpr int WDINV = WBETA + 256;         // 1/max(cnt,1) [256]
constexpr int WSEL  = WDINV + 256;         // cnt>0 ? 1 : 0 [256]
constexpr int WSW   = WSEL + 256;          // sw0[256], sw1[256]
constexpr int WCNTF = WSW + 512;           // cnt as float [256]
constexpr int WCOLP = WCNTF + 256;         // 257 ints (CSR col ptr)
constexpr int WROWS = WCOLP + 260;         // 4096 ints
constexpr int WHFRAG= WROWS + 4096;        // W_hh bf16 B-frags, 2048 x 16B
constexpr int WQFRAG= WHFRAG + 8192;       // RQ/P bf16 B-frags, 1024 x 16B

using bf16x8 = __attribute__((ext_vector_type(8))) short;   // 8 bf16 (4 VGPRs)
using f32x4  = __attribute__((ext_vector_type(4))) float;   // MFMA C/D

__device__ __forceinline__ float sigm(float x) { return 1.f / (1.f + __expf(-x)); }
__device__ __forceinline__ float tanh_(float x) { return 2.f / (1.f + __expf(-2.f * x)) - 1.f; }
__device__ __forceinline__ float blo(unsigned u) { return __uint_as_float(u << 16); }
__device__ __forceinline__ float bhi(unsigned u) { return __uint_as_float(u & 0xffff0000u); }
__device__ __forceinline__ unsigned f2bf(float f) {   // RNE bf16 bits
    unsigned u = __float_as_uint(f);
    return (u + 0x7fffu + ((u >> 16) & 1u)) >> 16;
}

// ---- K1 fused prep: blk 0 = tables; blk 1..8 = P/RQ/Q; blk 9..12 = W frags
__global__ __launch_bounds__(256) void k_prep(
    const int* __restrict__ conn, const float* __restrict__ cw,
    const float* __restrict__ Wih, const float* __restrict__ embW,
    const float* __restrict__ embB, const float* __restrict__ bih,
    const float* __restrict__ bhh, const float* __restrict__ Whh,
    const float* __restrict__ m1W, const float* __restrict__ m1b,
    const float* __restrict__ m2W, const float* __restrict__ m2b,
    float* __restrict__ ws) {
    int t = threadIdx.x, blk = blockIdx.x;
    if (blk >= 9) {
        // W_hh -> bf16 B-fragments for mfma_f32_16x16x32_bf16.
        int idx = (blk - 9) * 256 + t;        // 0..1023
        for (int f = idx; f < 2048; f += 1024) {
            int p = f >> 6, l = f & 63;
            int ct = p >> 1, ks = p & 1;
            const float* src = Whh + (ct * 16 + (l & 15)) * 64 + ks * 32 + ((l >> 4) << 3);
            unsigned u[4];
            #pragma unroll
            for (int q = 0; q < 4; ++q)
                u[q] = f2bf(src[2 * q]) | (f2bf(src[2 * q + 1]) << 16);
            ((uint4*)(ws + WHFRAG))[f] = make_uint4(u[0], u[1], u[2], u[3]);
        }
        return;
    }
    if (blk > 0) {
        __shared__ float sB[64 * 64];   // W2b = m2W rows 64..127
        bool isP = blk <= 4;
        int kbase = ((blk - 1) & 3) * 16;
        #pragma unroll
        for (int i = 0; i < 16; ++i) sB[t + 256 * i] = m2W[64 * 64 + t + 256 * i];
        __syncthreads();
        int j = t & 63, kl = t >> 6;
        #pragma unroll
        for (int r = 0; r < 4; ++r) {
            int k = kbase + kl * 4 + r;
            const float* arow = m1W + (isP ? k : (64 + k)) * 64;
            float acc = 0.f;
            #pragma unroll
            for (int m = 0; m < 64; m += 4) {
                float4 a4 = *(const float4*)(arow + m);
                acc = fmaf(a4.x, sB[m * 64 + j], acc);
                acc = fmaf(a4.y, sB[(m + 1) * 64 + j], acc);
                acc = fmaf(a4.z, sB[(m + 2) * 64 + j], acc);
                acc = fmaf(a4.w, sB[(m + 3) * 64 + j], acc);
            }
            if (isP) {
                ws[WP + k * 64 + j] = acc;
            } else {
                ws[WRM + k * 64 + j] = acc;                       // Q
                ws[WRQ + k * 64 + j] = acc + m2W[k * 64 + j];     // W2a + Q
            }
        }
        return;
    }
    __shared__ int s_cnt[N_];
    __shared__ float s_sw0[N_], s_sw1[N_];
    __shared__ int s_pos[N_];
    __shared__ float sU[3 * 64];
    __shared__ int s_wsum[4];
    s_cnt[t] = 0; s_sw0[t] = 0.f; s_sw1[t] = 0.f;
    __syncthreads();
    for (int e = t; e < E_; e += 256) {
        int c = conn[E_ + e] & 255;
        atomicAdd(&s_cnt[c], 1);
        atomicAdd(&s_sw0[c], cw[2 * e]);
        atomicAdd(&s_sw1[c], cw[2 * e + 1]);
    }
    __syncthreads();
    int lane = t & 63, wv = t >> 6;
    int val = s_cnt[t];
    int inc = val;
    #pragma unroll
    for (int d = 1; d < 64; d <<= 1) {
        int y = __shfl_up(inc, d);
        if (lane >= d) inc += y;
    }
    if (lane == 63) s_wsum[wv] = inc;
    __syncthreads();
    int wadd = 0;
    for (int w = 0; w < wv; ++w) wadd += s_wsum[w];
    int excl = wadd + inc - val;
    int* colp = (int*)(ws + WCOLP);
    colp[t] = excl;
    if (t == 0) colp[N_] = E_;
    s_pos[t] = excl;
    int cnt = val;
    ws[WCNTF + t] = (float)cnt;
    ws[WDINV + t] = 1.f / (float)(cnt > 1 ? cnt : 1);
    ws[WSEL + t]  = cnt > 0 ? 1.f : 0.f;
    ws[WSW + t]        = s_sw0[t];
    ws[WSW + N_ + t]   = s_sw1[t];
    float a = 0.f, b = 0.f;
    #pragma unroll
    for (int i = 0; i < 16; ++i) {
        float w = Wih[t * 16 + i];
        a += w * embW[i];
        b += w * embB[i];
    }
    ws[WALPHA + t] = a;
    ws[WBETA + t]  = b + bih[t] + bhh[t];
    __syncthreads();   // all s_pos[] initialized before rows fill
    int* rows = (int*)(ws + WROWS);
    for (int e = t; e < E_; e += 256) {
        int c = conn[E_ + e] & 255;
        int p = atomicAdd(&s_pos[c], 1);
        rows[p] = conn[e] & 255;
    }
    if (t < 192) {
        int part = t >> 6, j = t & 63;
        float acc = 0.f;
        #pragma unroll 8
        for (int m = 0; m < 64; ++m) {
            float w = (part == 0) ? m1W[128 * 64 + m]
                    : (part == 1) ? m1W[129 * 64 + m] : m1b[m];
            acc = fmaf(w, m2W[(64 + m) * 64 + j], acc);
        }
        sU[part * 64 + j] = acc;
    }
    __syncthreads();
    {
        int j = t & 63;
        float u0 = sU[j], u1 = sU[64 + j], u2 = sU[128 + j];
        float b2j = m2b[j];
        int vb = t >> 6;
        #pragma unroll 8
        for (int i = 0; i < 64; ++i) {
            int v = vb + i * 4;
            int cv = s_cnt[v];
            float dv = 1.f / (float)(cv > 1 ? cv : 1);
            float bb = s_sw0[v] * u0 + s_sw1[v] * u1 + (float)cv * u2;
            ws[WBIAS + v * 64 + j] = dv * bb + b2j;
        }
    }
}

// ---- K1b (second launch, stream-ordered after k_prep): RQ/P -> B-frags -----
// frag fi = mat*8 + ks*4 + ct (mat 0=RQ, 1=P); lane l, elem j holds
// M[ks*32 + (l>>4)*8 + j][ct*16 + (l&15)].
__global__ __launch_bounds__(256) void k_fragqp(float* __restrict__ ws) {
    int t = threadIdx.x;
    uint4* dst = (uint4*)(ws + WQFRAG);
    #pragma unroll
    for (int u0 = 0; u0 < 4; ++u0) {
        int u = u0 * 256 + t;
        int fi = u >> 6, l = u & 63;
        int mat = fi >> 3, ks = (fi >> 2) & 1, ct = fi & 3;
        const float* M = ws + (mat ? WP : WRQ);
        int kb = ks * 32 + ((l >> 4) << 3);
        int n = ct * 16 + (l & 15);
        unsigned uu[4];
        #pragma unroll
        for (int q = 0; q < 4; ++q)
            uu[q] = f2bf(M[(kb + 2 * q) * 64 + n])
                  | (f2bf(M[(kb + 2 * q + 1) * 64 + n]) << 16);
        dst[u] = make_uint4(uu[0], uu[1], uu[2], uu[3]);
    }
}

// ------- K2: MFMA LSTM. block = 16 seqs, 4 waves split the 16 col-tiles -----
// (frozen from round 10)
constexpr int HS = 72;   // h tile row stride in shorts (16B-aligned rows)

__global__ __launch_bounds__(256, 1) void k_lstm(
    const float* __restrict__ aqi, const float* __restrict__ ws,
    float* __restrict__ xout) {
    __shared__ __align__(16) short sW[2048 * 8];        // 32 KB: W frags
    __shared__ __align__(16) short sHhi[2][16 * HS];    // h_hi, 2 step-parity bufs
    __shared__ __align__(16) short sHlo[2][16 * HS];
    __shared__ float sX[24 * 16];                       // x[l][seq-row]
    int t = threadIdx.x;
    int w = t >> 6, lane = t & 63;
    int seq0 = blockIdx.x * 16;
    int b0 = seq0 >> 8, n0 = seq0 & 255;
    {
        const uint4* src = (const uint4*)(ws + WHFRAG);
        uint4* dst = (uint4*)sW;
        #pragma unroll
        for (int i = 0; i < 8; ++i) dst[t + 256 * i] = src[t + 256 * i];
    }
    for (int i = t; i < 384; i += 256) {
        int l = i >> 4, c = i & 15;
        sX[l * 16 + c] = aqi[(b0 * L_ + l) * N_ + n0 + c];
    }
    int c0 = lane & 15, quad = lane >> 4, q4 = quad * 4, q8 = quad * 8;
    float alF[4], beF[4];
    #pragma unroll
    for (int g = 0; g < 4; ++g) {
        alF[g] = ws[WALPHA + (4 * g + w) * 16 + c0];
        beF[g] = ws[WBETA  + (4 * g + w) * 16 + c0];
    }
    float cst[4] = {0.f, 0.f, 0.f, 0.f};
    bf16x8 hA[2][2] = {};
    __syncthreads();
    for (int l = 0; l < L_; ++l) {
        int buf = l & 1;
        f32x4 acc[4];
        #pragma unroll
        for (int g = 0; g < 4; ++g) {
            #pragma unroll
            for (int r = 0; r < 4; ++r)
                acc[g][r] = fmaf(sX[l * 16 + q4 + r], alF[g], beF[g]);
        }
        if (l > 0) {
            #pragma unroll
            for (int g = 0; g < 4; ++g) {
                int ct = 4 * g + w;
                #pragma unroll
                for (int ks = 0; ks < 2; ++ks) {
                    bf16x8 wb = *(const bf16x8*)&sW[((ct * 2 + ks) * 64 + lane) * 8];
                    acc[g] = __builtin_amdgcn_mfma_f32_16x16x32_bf16(
                        hA[0][ks], wb, acc[g], 0, 0, 0);
                    acc[g] = __builtin_amdgcn_mfma_f32_16x16x32_bf16(
                        hA[1][ks], wb, acc[g], 0, 0, 0);
                }
            }
        }
        float* orow = xout + ((size_t)(b0 * L_ + l) * N_ + n0) * 64;
        #pragma unroll
        for (int r = 0; r < 4; ++r) {
            float iv = sigm(acc[0][r]);
            float fv = sigm(acc[1][r]);
            float gv = tanh_(acc[2][r]);
            float ov = sigm(acc[3][r]);
            cst[r] = fmaf(fv, cst[r], iv * gv);
            float h = ov * tanh_(cst[r]);
            orow[(q4 + r) * 64 + w * 16 + c0] = h;
            unsigned hb = f2bf(h);
            float hf = __uint_as_float(hb << 16);
            unsigned lb = f2bf(h - hf);
            sHhi[buf][(q4 + r) * HS + w * 16 + c0] = (short)hb;
            sHlo[buf][(q4 + r) * HS + w * 16 + c0] = (short)lb;
        }
        __syncthreads();
        hA[0][0] = *(const bf16x8*)&sHhi[buf][c0 * HS + q8];
        hA[0][1] = *(const bf16x8*)&sHhi[buf][c0 * HS + 32 + q8];
        hA[1][0] = *(const bf16x8*)&sHlo[buf][c0 * HS + q8];
        hA[1][1] = *(const bf16x8*)&sHlo[buf][c0 * HS + 32 + q8];
    }
}

// ------- K4 v3: MFMA GNN. out = bias + X@RQ + (dinv*S)@P -------------------
// Scalar gather (cheap) -> Sd tile in LDS; both GEMMs on the matrix pipe with
// B-frags in registers. Weight LDS-read count per wave: 16 (was ~2048).
constexpr int XS = 72;   // bf16 LDS row stride (16B-aligned rows)

__global__ __launch_bounds__(256, 2) void k_graph(
    const float* __restrict__ ws, float* __restrict__ out) {
    __shared__ __align__(16) short Xl[N_ * XS];   // 36.9 KB
    __shared__ __align__(16) short Sl[N_ * XS];   // 36.9 KB
    int tg = blockIdx.x;
    int tid = threadIdx.x;
    int lane = tid & 63, w = tid >> 6;
    // stage X (f32 -> bf16 LDS, row-major A-layout)
    const float4* src = (const float4*)(out + tg * (N_ * 64));
    #pragma unroll
    for (int it = 0; it < 16; ++it) {
        int idx = tid + it * 256;
        float4 d = src[idx];
        int node = idx >> 4, col = (idx & 15) * 4;
        unsigned p0 = f2bf(d.x) | (f2bf(d.y) << 16);
        unsigned p1 = f2bf(d.z) | (f2bf(d.w) << 16);
        *(uint2*)&Xl[node * XS + col] = make_uint2(p0, p1);
    }
    __syncthreads();
    int v = tid;
    // ---- scalar gather S[64] = sum of in-neighbor x rows ----
    float S[64];
    #pragma unroll
    for (int k = 0; k < 64; ++k) S[k] = 0.f;
    {
        const int* colp = (const int*)(ws + WCOLP);
        const int* rows = (const int*)(ws + WROWS);
        int e1 = colp[v + 1];
        for (int e = colp[v]; e < e1; ++e) {
            int r = rows[e];
            const uint4* xp = (const uint4*)(Xl + r * XS);
            #pragma unroll
            for (int q = 0; q < 8; ++q) {
                uint4 u = xp[q];
                S[8 * q]     += blo(u.x); S[8 * q + 1] += bhi(u.x);
                S[8 * q + 2] += blo(u.y); S[8 * q + 3] += bhi(u.y);
                S[8 * q + 4] += blo(u.z); S[8 * q + 5] += bhi(u.z);
                S[8 * q + 6] += blo(u.w); S[8 * q + 7] += bhi(u.w);
            }
        }
    }
    float dinv = ws[WDINV + v];
    // write dinv*S as bf16 into Sl (A-layout row v)
    #pragma unroll
    for (int q = 0; q < 8; ++q) {
        unsigned a = f2bf(dinv * S[8 * q])     | (f2bf(dinv * S[8 * q + 1]) << 16);
        unsigned b = f2bf(dinv * S[8 * q + 2]) | (f2bf(dinv * S[8 * q + 3]) << 16);
        unsigned c = f2bf(dinv * S[8 * q + 4]) | (f2bf(dinv * S[8 * q + 5]) << 16);
        unsigned d = f2bf(dinv * S[8 * q + 6]) | (f2bf(dinv * S[8 * q + 7]) << 16);
        *(uint4*)&Sl[v * XS + q * 8] = make_uint4(a, b, c, d);
    }
    __syncthreads();
    // ---- MFMA phase: wave w owns row-tiles 4w..4w+3 ----
    bf16x8 bq[16];
    {
        const bf16x8* qf = (const bf16x8*)(ws + WQFRAG);
        #pragma unroll
        for (int i = 0; i < 16; ++i) bq[i] = qf[i * 64 + lane];
    }
    int c0 = lane & 15, quad = lane >> 4, q8 = quad * 8;
    const float* bias = ws + WBIAS;
    #pragma unroll
    for (int rti = 0; rti < 4; ++rti) {
        int rt = w * 4 + rti;
        const short* xr = &Xl[(rt * 16 + c0) * XS];
        const short* sr = &Sl[(rt * 16 + c0) * XS];
        bf16x8 ax0 = *(const bf16x8*)(xr + q8);
        bf16x8 ax1 = *(const bf16x8*)(xr + 32 + q8);
        bf16x8 as0 = *(const bf16x8*)(sr + q8);
        bf16x8 as1 = *(const bf16x8*)(sr + 32 + q8);
        #pragma unroll
        for (int ct = 0; ct < 4; ++ct) {
            f32x4 acc;
            #pragma unroll
            for (int r = 0; r < 4; ++r)
                acc[r] = bias[(rt * 16 + quad * 4 + r) * 64 + ct * 16 + c0];
            acc = __builtin_amdgcn_mfma_f32_16x16x32_bf16(ax0, bq[ct],      acc, 0, 0, 0);
            acc = __builtin_amdgcn_mfma_f32_16x16x32_bf16(ax1, bq[4 + ct],  acc, 0, 0, 0);
            acc = __builtin_amdgcn_mfma_f32_16x16x32_bf16(as0, bq[8 + ct],  acc, 0, 0, 0);
            acc = __builtin_amdgcn_mfma_f32_16x16x32_bf16(as1, bq[12 + ct], acc, 0, 0, 0);
            #pragma unroll
            for (int r = 0; r < 4; ++r)
                out[((size_t)tg * 256 + rt * 16 + quad * 4 + r) * 64 + ct * 16 + c0]
                    = acc[r];
        }
    }
    // ---- rare correction (cnt==0 -> W2a, not W2a+Q): essentially never ----
    float sel = ws[WSEL + v];
    if (__syncthreads_or(sel < 0.5f)) {
        if (sel < 0.5f) {
            float* og = out + ((size_t)tg * 256 + v) * 64;
            #pragma unroll
            for (int jc = 0; jc < 4; ++jc) {
                float corr[16];
                #pragma unroll
                for (int j = 0; j < 16; ++j) corr[j] = 0.f;
                #pragma unroll
                for (int k = 0; k < 64; ++k) {
                    unsigned hv = (unsigned short)Xl[v * XS + k];
                    float xk = __uint_as_float(hv << 16);
                    const float* Q = ws + WRM + k * 64 + jc * 16;
                    #pragma unroll
                    for (int j = 0; j < 16; ++j) corr[j] += xk * Q[j];
                }
                #pragma unroll
                for (int j = 0; j < 16; ++j) og[jc * 16 + j] -= corr[j];
            }
        }
    }
}

extern "C" void kernel_launch(void* const* d_in, const int* in_sizes, int n_in,
                              void* d_out, int out_size, void* d_ws, size_t ws_size,
                              hipStream_t stream) {
    const float* aqi  = (const float*)d_in[0];
    const int*   conn = (const int*)d_in[1];
    const float* cw   = (const float*)d_in[2];
    const float* embW = (const float*)d_in[3];
    const float* embB = (const float*)d_in[4];
    const float* Wih  = (const float*)d_in[5];
    const float* Whh  = (const float*)d_in[6];
    const float* bih  = (const float*)d_in[7];
    const float* bhh  = (const float*)d_in[8];
    const float* m1W  = (const float*)d_in[9];
    const float* m1b  = (const float*)d_in[10];
    const float* m2W  = (const float*)d_in[11];
    const float* m2b  = (const float*)d_in[12];
    float* ws  = (float*)d_ws;
    float* out = (float*)d_out;

    k_prep<<<dim3(13), dim3(256), 0, stream>>>(conn, cw, Wih, embW, embB, bih, bhh,
                                               Whh, m1W, m1b, m2W, m2b, ws);
    k_fragqp<<<dim3(1), dim3(256), 0, stream>>>(ws);
    k_lstm<<<dim3(256), dim3(256), 0, stream>>>(aqi, ws, out);
    k_graph<<<dim3(T_), dim3(256), 0, stream>>>(ws, out);
}